// Round 1
// 477.562 us; speedup vs baseline: 1.1260x; 1.1260x over previous
//
#include <hip/hip_runtime.h>
#include <math.h>

// OmniRobotPhysics: B=8192 independent trajectories, T=1024 sequential steps.
// One thread per trajectory (128 wave64 total -> latency-bound; ~754 cy/step in R2).
// R2 -> R3 changes:
//  - body-frame recurrence: state (vxb,vyb,om) updated via exact identity
//      vb' = R(-dtheta) (vb + ab*DT),  dtheta = om'*DT  (small; 3-term Taylor)
//    This removes the full Cody-Waite sincos AND the world<->body transform
//    from the serial dependency chain. (c,s)=sincos(th) maintained by the
//    same incremental rotation (+1 Newton renorm/step); they feed outputs only.
//  - real register ping-pong double-buffer for cmd: two named float4[12]
//    buffers, unconditional clamped-index prefetch, outer loop unrolled x2.
//    (R2's nxt=cur-then-conditional-overwrite collapsed to 88 VGPRs => the
//    compiler serialized load latency into the chunk.)

#define MASS_F 2.8f
#define DT_F 0.016f

// F F^T entries (angles {60,130,230,300} deg, R=0.09):
#define M00_F 2.6736481776669306f
#define M11_F 1.3263518223330697f
#define M12_F (-0.025701769743577074f)
#define M22_F 0.0324f

#define PI_F 3.14159265358979323846f
#define TWO_PI_F 6.28318530717958647692f

#define CHUNK 16   // steps per chunk; 16*3 floats = 12 float4 per lane

__device__ __forceinline__ float softplus_f(float x) {
    float ax = fabsf(x);
    return fmaxf(x, 0.0f) + log1pf(expf(-ax));
}

__device__ __forceinline__ float sgn_f(float v) {
    return (v > 0.0f ? 1.0f : 0.0f) - (v < 0.0f ? 1.0f : 0.0f);
}

// Full-range sin/cos: used ONCE for th0 (and in the generic tail).
__device__ __forceinline__ void fast_sincos(float th, float* sp, float* cp) {
    const float INV_PIO2 = 0.63661977236758134f;
    const float PIO2_HI  = 1.57079637050628662109375f;   // fp32(pi/2)
    const float PIO2_LO  = -4.37113900018624283e-8f;     // pi/2 - PIO2_HI
    float kf = rintf(th * INV_PIO2);
    int   k  = (int)kf;
    float r  = fmaf(-kf, PIO2_HI, th);
    r        = fmaf(-kf, PIO2_LO, r);
    float r2 = r * r;
    float ps = fmaf(r2, 2.7183114e-6f, -1.9515296e-4f);
    ps = fmaf(r2, ps, 8.3333310e-3f);
    ps = fmaf(r2, ps, -1.6666667e-1f);
    float sr = fmaf(r * r2, ps, r);
    float pc = fmaf(r2, 2.4760495e-5f, -1.3888889e-3f);
    pc = fmaf(r2, pc, 4.1666668e-2f);
    pc = fmaf(r2, pc, -0.5f);
    float cr = fmaf(r2, pc, 1.0f);
    int n = k & 3;
    float s = (n == 0) ? sr : (n == 1) ? cr : (n == 2) ? -sr : -cr;
    float c = (n == 0) ? cr : (n == 1) ? -sr : (n == 2) ? -cr : sr;
    *sp = s;
    *cp = c;
}

struct Coef {
    float A00, A11, A12, A22;
    float dv0, dv1, dv2;
    float dc0, dc1, dc2;
    float dx, dy, inv_mass, inv_inertia;
};

// One 16-step chunk, body-frame recurrence. cb holds 16 steps of cmd (48 floats).
__device__ __forceinline__ void step_chunk(const float4 (&cb)[12], float* __restrict__ op,
                                           float& x, float& y, float& th,
                                           float& cth, float& sth,
                                           float& vxb, float& vyb, float& om,
                                           const Coef& K)
{
    float u[3 * CHUNK];
    #pragma unroll
    for (int i = 0; i < 12; ++i) {
        u[4 * i + 0] = cb[i].x;
        u[4 * i + 1] = cb[i].y;
        u[4 * i + 2] = cb[i].z;
        u[4 * i + 3] = cb[i].w;
    }

    #pragma unroll
    for (int j = 0; j < CHUNK; ++j) {
        const float u0 = u[3 * j + 0];
        const float u1 = u[3 * j + 1];
        const float u2 = u[3 * j + 2];

        const float ex = u0 - vxb;
        const float ey = u1 - vyb;
        const float ez = u2 - om;

        const float Fx = K.A00 * ex               - K.dv0 * vxb - K.dc0 * sgn_f(vxb);
        const float Fy = K.A11 * ey + K.A12 * ez  - K.dv1 * vyb - K.dc1 * sgn_f(vyb);
        const float Tz = K.A12 * ey + K.A22 * ez  - K.dv2 * om  - K.dc2 * sgn_f(om);

        const float Tc = Tz - (K.dx * Fy - K.dy * Fx);
        const float al = Tc * K.inv_inertia;
        const float om2 = om * om;

        const float axb = Fx * K.inv_mass - al * K.dy - om2 * K.dx;
        const float ayb = Fy * K.inv_mass + al * K.dx - om2 * K.dy;

        const float nom = om + al * DT_F;
        const float wx  = vxb + axb * DT_F;   // new world velocity, OLD body frame
        const float wy  = vyb + ayb * DT_F;

        // rotate into the new frame: dtheta = nom*DT, |dtheta| small (damped om)
        const float dth = nom * DT_F;
        const float d2  = dth * dth;
        float sp = fmaf(d2, 8.3333333e-3f, -1.6666667e-1f);  // d^4/120 - d^2/6
        sp = fmaf(d2, sp, 1.0f);
        const float sd = dth * sp;                            // sin(dth)
        float cp = fmaf(d2, 4.1666667e-2f, -0.5f);            // d^4/24 - d^2/2
        const float cd = fmaf(d2, cp, 1.0f);                  // cos(dth)

        const float nvxb = fmaf(cd, wx,  sd * wy);            // R(-dth) * w
        const float nvyb = fmaf(cd, wy, -sd * wx);

        // world-frame outputs (use OLD c,s: v' = R(th) * w)
        const float nvx = fmaf(cth, wx, -sth * wy);
        const float nvy = fmaf(sth, wx,  cth * wy);

        // advance (c,s) by the same rotation; 1 Newton renorm step
        float nc = fmaf(cth, cd, -sth * sd);
        float ns = fmaf(sth, cd,  cth * sd);
        const float rn = fmaf(-0.5f, fmaf(nc, nc, ns * ns), 1.5f);
        nc *= rn;
        ns *= rn;

        x = fmaf(nvx, DT_F, x);
        y = fmaf(nvy, DT_F, y);
        float nth = th + dth;
        nth = (nth >  PI_F) ? nth - TWO_PI_F : nth;
        nth = (nth < -PI_F) ? nth + TWO_PI_F : nth;

        vxb = nvxb; vyb = nvyb; om = nom; th = nth; cth = nc; sth = ns;

        float* ot = op + 6 * j;
        ((float2*)ot)[0] = make_float2(x, y);
        ((float2*)ot)[1] = make_float2(nth, nvx);
        ((float2*)ot)[2] = make_float2(nvy, nom);
    }
}

__global__ __launch_bounds__(64, 1)
void omni_robot_kernel(const float* __restrict__ init_state,   // (B, 6)
                       const float* __restrict__ cmd_all,      // (B, T, 3)
                       const float* __restrict__ com_offset,   // (2,)
                       const float* __restrict__ inertia_p,    // (1,)
                       const float* __restrict__ gain_p,       // (1,)
                       const float* __restrict__ grip_p,       // (1,)
                       const float* __restrict__ drag_v_p,     // (3,)
                       const float* __restrict__ drag_c_p,     // (3,)
                       float* __restrict__ out,                // (B, T+1, 6)
                       int B, int T)
{
    const int b = blockIdx.x * blockDim.x + threadIdx.x;
    if (b >= B) return;

    const float inertia = softplus_f(inertia_p[0]) + 1e-4f;
    const float gain    = softplus_f(gain_p[0]);
    const float grip    = softplus_f(grip_p[0]);

    Coef K;
    K.A00 = gain * M00_F + grip;
    K.A11 = gain * M11_F + grip;
    K.A12 = gain * M12_F;
    K.A22 = gain * M22_F + grip;
    K.dv0 = softplus_f(drag_v_p[0]);
    K.dv1 = softplus_f(drag_v_p[1]);
    K.dv2 = softplus_f(drag_v_p[2]);
    K.dc0 = softplus_f(drag_c_p[0]);
    K.dc1 = softplus_f(drag_c_p[1]);
    K.dc2 = softplus_f(drag_c_p[2]);
    K.dx  = com_offset[0];
    K.dy  = com_offset[1];
    K.inv_mass    = 1.0f / MASS_F;
    K.inv_inertia = 1.0f / inertia;

    const float* st = init_state + (size_t)b * 6;
    float x  = st[0];
    float y  = st[1];
    float th = st[2];
    float vx = st[3];
    float vy = st[4];
    float om = st[5];

    const float* __restrict__ cmd = cmd_all + (size_t)b * T * 3;
    float* __restrict__ o = out + (size_t)b * (size_t)(T + 1) * 6;

    ((float2*)o)[0] = make_float2(x, y);
    ((float2*)o)[1] = make_float2(th, vx);
    ((float2*)o)[2] = make_float2(vy, om);

    // initial frame (once, off the recurrence)
    float cth, sth;
    fast_sincos(th, &sth, &cth);
    float vxb = fmaf(vx, cth, vy * sth);
    float vyb = fmaf(vy, cth, -vx * sth);

    // cmd base: b*12288 bytes -> 16B aligned; 12 float4 per chunk.
    const float4* __restrict__ cmd4 = reinterpret_cast<const float4*>(cmd);
    const int nch = T / CHUNK;
    float* op = o + 6;   // output slot for t=1

    if (nch > 0) {
        float4 bufA[12], bufB[12];
        #pragma unroll
        for (int i = 0; i < 12; ++i) bufA[i] = cmd4[i];

        for (int ch = 0; ch < nch; ch += 2) {
            // prefetch chunk ch+1 into B (clamped -> always valid, unconditional)
            {
                int pf = ch + 1; if (pf > nch - 1) pf = nch - 1;
                const float4* __restrict__ src = cmd4 + (size_t)pf * 12;
                #pragma unroll
                for (int i = 0; i < 12; ++i) bufB[i] = src[i];
            }
            step_chunk(bufA, op, x, y, th, cth, sth, vxb, vyb, om, K);
            op += 6 * CHUNK;

            // prefetch chunk ch+2 into A (clamped)
            {
                int pf = ch + 2; if (pf > nch - 1) pf = nch - 1;
                const float4* __restrict__ src = cmd4 + (size_t)pf * 12;
                #pragma unroll
                for (int i = 0; i < 12; ++i) bufA[i] = src[i];
            }
            if (ch + 1 < nch) {
                step_chunk(bufB, op, x, y, th, cth, sth, vxb, vyb, om, K);
                op += 6 * CHUNK;
            }
        }
    }

    // generic tail (T % CHUNK != 0); dead for T=1024. World-frame scalar loop.
    if (nch * CHUNK < T) {
        vx = fmaf(cth, vxb, -sth * vyb);
        vy = fmaf(sth, vxb,  cth * vyb);
        for (int t = nch * CHUNK; t < T; ++t) {
            const float u0 = cmd[3 * t + 0];
            const float u1 = cmd[3 * t + 1];
            const float u2 = cmd[3 * t + 2];
            float c, s;
            fast_sincos(th, &s, &c);
            const float vxb_t = vx * c + vy * s;
            const float vyb_t = vy * c - vx * s;
            const float ex = u0 - vxb_t;
            const float ey = u1 - vyb_t;
            const float ez = u2 - om;
            const float Fx = K.A00 * ex               - K.dv0 * vxb_t - K.dc0 * sgn_f(vxb_t);
            const float Fy = K.A11 * ey + K.A12 * ez  - K.dv1 * vyb_t - K.dc1 * sgn_f(vyb_t);
            const float Tz = K.A12 * ey + K.A22 * ez  - K.dv2 * om    - K.dc2 * sgn_f(om);
            const float Tc = Tz - (K.dx * Fy - K.dy * Fx);
            const float al = Tc * K.inv_inertia;
            const float om2 = om * om;
            const float axb = Fx * K.inv_mass - al * K.dy - om2 * K.dx;
            const float ayb = Fy * K.inv_mass + al * K.dx - om2 * K.dy;
            const float axw = axb * c - ayb * s;
            const float ayw = axb * s + ayb * c;
            vx = vx + axw * DT_F;
            vy = vy + ayw * DT_F;
            om = om + al * DT_F;
            x  = x + vx * DT_F;
            y  = y + vy * DT_F;
            th = th + om * DT_F;
            th = (th >  PI_F) ? th - TWO_PI_F : th;
            th = (th < -PI_F) ? th + TWO_PI_F : th;
            float* ot = o + (size_t)(t + 1) * 6;
            ((float2*)ot)[0] = make_float2(x, y);
            ((float2*)ot)[1] = make_float2(th, vx);
            ((float2*)ot)[2] = make_float2(vy, om);
        }
    }
}

extern "C" void kernel_launch(void* const* d_in, const int* in_sizes, int n_in,
                              void* d_out, int out_size, void* d_ws, size_t ws_size,
                              hipStream_t stream) {
    const float* init_state = (const float*)d_in[0];
    const float* cmd        = (const float*)d_in[1];
    const float* com_offset = (const float*)d_in[2];
    const float* inertia_p  = (const float*)d_in[3];
    const float* gain_p     = (const float*)d_in[4];
    const float* grip_p     = (const float*)d_in[5];
    const float* drag_v_p   = (const float*)d_in[6];
    const float* drag_c_p   = (const float*)d_in[7];
    float* out = (float*)d_out;

    const int B = in_sizes[0] / 6;
    const int T = in_sizes[1] / (3 * B);

    const int block = 64;
    const int grid = (B + block - 1) / block;
    hipLaunchKernelGGL(omni_robot_kernel, dim3(grid), dim3(block), 0, stream,
                       init_state, cmd, com_offset, inertia_p, gain_p, grip_p,
                       drag_v_p, drag_c_p, out, B, T);
}